// Round 11
// baseline (133.336 us; speedup 1.0000x reference)
//
#include <hip/hip_runtime.h>
#include <hip/hip_bf16.h>

#define N_NODES_C 50000
#define N_EDGES_C 800000
#define N_GRAPHS_C 64
#define NBKT 782           // buckets of 64 nodes: (50000+63)>>6
#define BKTP 784           // padded bucket count
#define CHUNK 4096         // edges per histogram/scatter block
#define NBLK_E 196         // 196*4096 = 802816 >= 800000

typedef __attribute__((ext_vector_type(8))) short bf16x8;
typedef __attribute__((ext_vector_type(4))) float f32x4;

__device__ __forceinline__ unsigned short f2bf(float f) {
    unsigned u = __float_as_uint(f);
    unsigned r = (u + 0x7FFFu + ((u >> 16) & 1u)) >> 16;   // RNE
    return (unsigned short)r;
}

// ---------------- pass A: per-block LDS histograms over coarse buckets
__global__ __launch_bounds__(256) void k_hist(
    const int* __restrict__ src, const int* __restrict__ dst,
    int* __restrict__ hmatD, int* __restrict__ hmatS, int nE)
{
    __shared__ int hD[BKTP], hS[BKTP];
    const int tid = threadIdx.x, blk = blockIdx.x;
    for (int i = tid; i < BKTP; i += 256) { hD[i] = 0; hS[i] = 0; }
    __syncthreads();
    const int base = blk * CHUNK;
    for (int i = tid; i < CHUNK; i += 256) {
        int e = base + i;
        if (e < nE) {
            atomicAdd(&hD[dst[e] >> 6], 1);
            atomicAdd(&hS[src[e] >> 6], 1);
        }
    }
    __syncthreads();
    for (int i = tid; i < BKTP; i += 256) {
        hmatD[blk * BKTP + i] = hD[i];
        hmatS[blk * BKTP + i] = hS[i];
    }
}

// ------- pass B: bucket totals (coalesced row sums) + scan; zeroes accbuf
__global__ __launch_bounds__(1024) void k_bscan(
    const int* __restrict__ hmatD, const int* __restrict__ hmatS,
    int* __restrict__ bbaseD, int* __restrict__ bbaseS,
    float* __restrict__ accbuf)
{
    __shared__ int part[1024];
    const int tid = threadIdx.x;
    const int* hm = blockIdx.x ? hmatS : hmatD;
    int* bb = blockIdx.x ? bbaseS : bbaseD;
    if (blockIdx.x == 0) accbuf[tid] = 0.f;   // zero [64][16] graph accumulator
    int v = 0;
    if (tid < NBKT)
        for (int blk = 0; blk < NBLK_E; ++blk) v += hm[blk * BKTP + tid];
    part[tid] = v;
    __syncthreads();
    for (int off = 1; off < 1024; off <<= 1) {
        int t = (tid >= off) ? part[tid - off] : 0;
        __syncthreads();
        part[tid] += t;
        __syncthreads();
    }
    if (tid < NBKT) bb[tid] = part[tid] - v;
    if (tid == NBKT - 1) bb[NBKT] = part[tid];
}

// ------- pass B3: per-(bucket,block) scatter offsets (+ w1/w2 frag conv)
__global__ __launch_bounds__(256) void k_boff(
    const int* __restrict__ hmatD, const int* __restrict__ hmatS,
    const int* __restrict__ bbaseD, const int* __restrict__ bbaseS,
    int* __restrict__ offmatD, int* __restrict__ offmatS,
    const float* __restrict__ W1, const float* __restrict__ W2,
    unsigned short* __restrict__ w1f, unsigned short* __restrict__ w2f)
{
    __shared__ int part[256];
    const int b = blockIdx.x, tid = threadIdx.x;
    const int* hm = blockIdx.y ? hmatS : hmatD;
    const int* bb = blockIdx.y ? bbaseS : bbaseD;
    int* om = blockIdx.y ? offmatS : offmatD;
    int v = (tid < NBLK_E) ? hm[tid * BKTP + b] : 0;
    part[tid] = v;
    __syncthreads();
    for (int off = 1; off < 256; off <<= 1) {
        int t = (tid >= off) ? part[tid - off] : 0;
        __syncthreads();
        part[tid] += t;
        __syncthreads();
    }
    if (tid < NBLK_E) om[tid * BKTP + b] = bb[b] + part[tid] - v;

    // side job on 9 spare S-side blocks: W1/W2 -> MFMA B-fragment order
    if (blockIdx.y == 1 && b < 9) {
        int t = b * 256 + tid;
        if (t < 2048) {
            int kk = t >> 9, nt = (t >> 6) & 7, l = t & 63;
            int kb = kk * 32 + ((l >> 4) << 3), n = nt * 16 + (l & 15);
            ushort4 lo, hi;
            lo.x = f2bf(W1[(kb + 0) * 128 + n]); lo.y = f2bf(W1[(kb + 1) * 128 + n]);
            lo.z = f2bf(W1[(kb + 2) * 128 + n]); lo.w = f2bf(W1[(kb + 3) * 128 + n]);
            hi.x = f2bf(W1[(kb + 4) * 128 + n]); hi.y = f2bf(W1[(kb + 5) * 128 + n]);
            hi.z = f2bf(W1[(kb + 6) * 128 + n]); hi.w = f2bf(W1[(kb + 7) * 128 + n]);
            ((ushort4*)(w1f + t * 8))[0] = lo;
            ((ushort4*)(w1f + t * 8))[1] = hi;
        } else if (t < 2304) {
            int t2 = t - 2048;
            int kk = t2 >> 6, l = t2 & 63;
            int kb = kk * 32 + ((l >> 4) << 3), n = l & 15;
            ushort4 lo, hi;
            lo.x = f2bf(W2[(kb + 0) * 16 + n]); lo.y = f2bf(W2[(kb + 1) * 16 + n]);
            lo.z = f2bf(W2[(kb + 2) * 16 + n]); lo.w = f2bf(W2[(kb + 3) * 16 + n]);
            hi.x = f2bf(W2[(kb + 4) * 16 + n]); hi.y = f2bf(W2[(kb + 5) * 16 + n]);
            hi.z = f2bf(W2[(kb + 6) * 16 + n]); hi.w = f2bf(W2[(kb + 7) * 16 + n]);
            ((ushort4*)(w2f + t2 * 8))[0] = lo;
            ((ushort4*)(w2f + t2 * 8))[1] = hi;
        }
    }
}

// ---------------- pass C: scatter edges into buckets (LDS cursors only)
__global__ __launch_bounds__(256) void k_scat(
    const int* __restrict__ src, const int* __restrict__ dst,
    const int* __restrict__ offmatD, const int* __restrict__ offmatS,
    unsigned* __restrict__ ed, unsigned char* __restrict__ es, int nE)
{
    __shared__ int curD[BKTP], curS[BKTP];
    const int tid = threadIdx.x, blk = blockIdx.x;
    for (int i = tid; i < BKTP; i += 256) {
        curD[i] = offmatD[blk * BKTP + i];
        curS[i] = offmatS[blk * BKTP + i];
    }
    __syncthreads();
    const int base = blk * CHUNK;
    for (int i = tid; i < CHUNK; i += 256) {
        int e = base + i;
        if (e < nE) {
            unsigned s = (unsigned)src[e], d = (unsigned)dst[e];
            int pD = atomicAdd(&curD[d >> 6], 1);
            ed[pD] = (d << 16) | s;
            int pS = atomicAdd(&curS[s >> 6], 1);
            es[pS] = (unsigned char)(s & 63u);
        }
    }
}

// ------ pass D: per-bucket finalize (D: rowptr/rsI/csr_src | S: rsO + xs conv)
__global__ __launch_bounds__(256) void k_bucket(
    const unsigned* __restrict__ ed, const unsigned char* __restrict__ es,
    const int* __restrict__ bbaseD, const int* __restrict__ bbaseS,
    const float* __restrict__ x,
    int* __restrict__ rowptr, float* __restrict__ rsI, float* __restrict__ rsO,
    unsigned short* __restrict__ csr_src, unsigned short* __restrict__ xs, int nV)
{
    __shared__ int cnt[64], cur[64];
    __shared__ float rs[64];
    const int tid = threadIdx.x;
    const int side = (blockIdx.x >= NBKT);
    const int b = side ? blockIdx.x - NBKT : blockIdx.x;

    if (tid < 64) cnt[tid] = 0;
    __syncthreads();

    if (!side) {
        const int lo = bbaseD[b], hi = bbaseD[b + 1];
        for (int j = lo + tid; j < hi; j += 256)
            atomicAdd(&cnt[(ed[j] >> 16) & 63u], 1);
        __syncthreads();
        if (tid < 64) {
            int c = cnt[tid];
            int v = c;
#pragma unroll
            for (int off = 1; off < 64; off <<= 1) {
                int n = __shfl_up(v, off, 64);
                if (tid >= off) v += n;
            }
            int excl = v - c;
            int node = b * 64 + tid;
            if (node <= nV) rowptr[node] = lo + excl;
            if (node < nV) rsI[node] = rsqrtf((float)max(c, 1));
            cur[tid] = excl;
        }
        __syncthreads();
        for (int j = lo + tid; j < hi; j += 256) {
            unsigned v = ed[j];
            int p = atomicAdd(&cur[(v >> 16) & 63u], 1);
            csr_src[lo + p] = (unsigned short)(v & 0xFFFFu);
        }
    } else {
        const int lo = bbaseS[b], hi = bbaseS[b + 1];
        for (int j = lo + tid; j < hi; j += 256)
            atomicAdd(&cnt[es[j]], 1);
        __syncthreads();
        if (tid < 64) {
            int node = b * 64 + tid;
            float r = rsqrtf((float)max(cnt[tid], 1));
            if (node < nV) rsO[node] = r;
            rs[tid] = r;
        }
        __syncthreads();
        // convert this bucket's 64 rows: xs = bf16(x * rsO)
        for (int q = tid; q < 64 * 32; q += 256) {
            int n = q >> 5, c = q & 31;
            int node = b * 64 + n;
            if (node < nV) {
                float wgt = rs[n];
                float4 a = ((const float4*)(x + (size_t)node * 128))[c];
                ushort4 o;
                o.x = f2bf(a.x * wgt); o.y = f2bf(a.y * wgt);
                o.z = f2bf(a.z * wgt); o.w = f2bf(a.w * wgt);
                ((ushort4*)(xs + (size_t)node * 128))[c] = o;
            }
        }
    }
}

#define ACC8(vv)                                         \
    acc[0] += __uint_as_float((vv).x << 16);             \
    acc[1] += __uint_as_float((vv).x & 0xFFFF0000u);     \
    acc[2] += __uint_as_float((vv).y << 16);             \
    acc[3] += __uint_as_float((vv).y & 0xFFFF0000u);     \
    acc[4] += __uint_as_float((vv).z << 16);             \
    acc[5] += __uint_as_float((vv).z & 0xFFFF0000u);     \
    acc[6] += __uint_as_float((vv).w << 16);             \
    acc[7] += __uint_as_float((vv).w & 0xFFFF0000u);

// ---- fused: gather-to-LDS + MFMA layer1 + relu + MFMA layer2 -> y (bf16)
// 782 blocks x 4 waves; wave w owns rows w*16..w*16+15 of its 64-row tile.
// All LDS traffic is wave-local: NO barriers needed.
__global__ __launch_bounds__(256) void k_fused(
    const unsigned short* __restrict__ xs, const int* __restrict__ rowptr,
    const unsigned short* __restrict__ csr_src, const float* __restrict__ rsI,
    const float* __restrict__ b1, const unsigned short* __restrict__ w1f,
    const unsigned short* __restrict__ w2f, const float* __restrict__ rsO,
    unsigned short* __restrict__ y, int nV)
{
    __shared__ __align__(16) unsigned short Al[64 * 136];   // padded rows (272 B)
    const int tid = threadIdx.x;
    const int w = tid >> 6, l = tid & 63;
    const int g = l >> 4, fl = l & 15;        // 4 edge-groups x 16 feature-lanes
    const int row0 = blockIdx.x * 64;

    // ---- phase A: gather 16 rows (agg1 = rsI * sum xs[src]) into LDS
    for (int n = 0; n < 16; ++n) {
        int r = w * 16 + n;
        int v = row0 + r;
        float acc[8];
#pragma unroll
        for (int k = 0; k < 8; ++k) acc[k] = 0.f;
        float ri = 0.f;
        if (v < nV) {
            ri = rsI[v];
            int beg = rowptr[v], end = rowptr[v + 1];
            int j = beg + g;
            while (j + 12 < end) {
                int s0 = csr_src[j], s1 = csr_src[j + 4], s2 = csr_src[j + 8], s3 = csr_src[j + 12];
                uint4 w0 = *(const uint4*)(xs + (size_t)s0 * 128 + fl * 8);
                uint4 w1 = *(const uint4*)(xs + (size_t)s1 * 128 + fl * 8);
                uint4 w2 = *(const uint4*)(xs + (size_t)s2 * 128 + fl * 8);
                uint4 w3 = *(const uint4*)(xs + (size_t)s3 * 128 + fl * 8);
                ACC8(w0); ACC8(w1); ACC8(w2); ACC8(w3);
                j += 16;
            }
            while (j + 4 < end) {
                int s0 = csr_src[j], s1 = csr_src[j + 4];
                uint4 w0 = *(const uint4*)(xs + (size_t)s0 * 128 + fl * 8);
                uint4 w1 = *(const uint4*)(xs + (size_t)s1 * 128 + fl * 8);
                ACC8(w0); ACC8(w1);
                j += 8;
            }
            if (j < end) {
                int s0 = csr_src[j];
                uint4 w0 = *(const uint4*)(xs + (size_t)s0 * 128 + fl * 8);
                ACC8(w0);
            }
        }
#pragma unroll
        for (int k = 0; k < 8; ++k) {
            acc[k] += __shfl_xor(acc[k], 16, 64);
            acc[k] += __shfl_xor(acc[k], 32, 64);
        }
        if (g < 2) {
            ushort4 o;
            o.x = f2bf(acc[g * 4 + 0] * ri);
            o.y = f2bf(acc[g * 4 + 1] * ri);
            o.z = f2bf(acc[g * 4 + 2] * ri);
            o.w = f2bf(acc[g * 4 + 3] * ri);
            *(ushort4*)(&Al[r * 136 + fl * 8 + g * 4]) = o;
        }
    }

    // ---- phase B: layer-1 MFMA (A from LDS — wave-local rows)
    const int lr = fl, lg = g;
    bf16x8 a[4];
#pragma unroll
    for (int kk = 0; kk < 4; ++kk)
        a[kk] = *(const bf16x8*)(&Al[(w * 16 + lr) * 136 + kk * 32 + lg * 8]);

    f32x4 acc1[8];
#pragma unroll
    for (int nt = 0; nt < 8; ++nt) acc1[nt] = (f32x4){0.f, 0.f, 0.f, 0.f};
#pragma unroll
    for (int nt = 0; nt < 8; ++nt)
#pragma unroll
        for (int kk = 0; kk < 4; ++kk) {
            bf16x8 b = *(const bf16x8*)(w1f + ((kk * 8 + nt) * 64 + l) * 8);
            acc1[nt] = __builtin_amdgcn_mfma_f32_16x16x32_bf16(a[kk], b, acc1[nt], 0, 0, 0);
        }

    // epilogue 1: +b1, relu, bf16 -> back into Al (wave-local rows)
#pragma unroll
    for (int nt = 0; nt < 8; ++nt) {
        float bb = b1[nt * 16 + lr];
#pragma unroll
        for (int i = 0; i < 4; ++i) {
            float h = fmaxf(acc1[nt][i] + bb, 0.f);
            Al[(w * 16 + lg * 4 + i) * 136 + nt * 16 + lr] = f2bf(h);
        }
    }

    // ---- phase C: layer-2 MFMA (N=16, K=128), y = (h1@W2)*rsO as bf16
    f32x4 acc2 = (f32x4){0.f, 0.f, 0.f, 0.f};
#pragma unroll
    for (int kk = 0; kk < 4; ++kk) {
        bf16x8 a2 = *(const bf16x8*)(&Al[(w * 16 + lr) * 136 + kk * 32 + lg * 8]);
        bf16x8 b2 = *(const bf16x8*)(w2f + (kk * 64 + l) * 8);
        acc2 = __builtin_amdgcn_mfma_f32_16x16x32_bf16(a2, b2, acc2, 0, 0, 0);
    }
#pragma unroll
    for (int i = 0; i < 4; ++i) {
        int r = row0 + w * 16 + lg * 4 + i;
        if (r < nV) y[(size_t)r * 16 + lr] = f2bf(acc2[i] * rsO[r]);
    }
}

// --------- fused layer-2 agg + rsI scale + per-graph pooling
__global__ __launch_bounds__(256) void k_agg2p(
    const unsigned short* __restrict__ y, const int* __restrict__ rowptr,
    const unsigned short* __restrict__ csr_src, const float* __restrict__ rsI,
    const int* __restrict__ gid, float* __restrict__ accbuf, int nV)
{
    const int tid = threadIdx.x;
    const int lane = tid & 63, f = lane & 15, g4 = lane >> 4;
    const int wid = blockIdx.x * 4 + (tid >> 6);
    int v0 = wid * 8;
    if (v0 >= nV) return;
    int vend = min(v0 + 8, nV);
    float racc = 0.f;
    int curg = gid[v0];
    for (int v = v0; v < vend; ++v) {
        int beg = rowptr[v], end = rowptr[v + 1];
        float acc = 0.f;
        int j = beg + g4;
        while (j + 4 < end) {
            int s0 = csr_src[j], s1 = csr_src[j + 4];
            unsigned u0 = y[(size_t)s0 * 16 + f];
            unsigned u1 = y[(size_t)s1 * 16 + f];
            acc += __uint_as_float(u0 << 16) + __uint_as_float(u1 << 16);
            j += 8;
        }
        if (j < end) {
            unsigned u = y[(size_t)csr_src[j] * 16 + f];
            acc += __uint_as_float(u << 16);
        }
        acc += __shfl_xor(acc, 16, 64);
        acc += __shfl_xor(acc, 32, 64);
        int gg = gid[v];
        if (gg != curg) {
            if (g4 == 0 && racc != 0.f) unsafeAtomicAdd(&accbuf[curg * 16 + f], racc);
            racc = 0.f;
            curg = gg;
        }
        racc += acc * rsI[v];
    }
    if (g4 == 0 && racc != 0.f) unsafeAtomicAdd(&accbuf[curg * 16 + f], racc);
}

// ------------------------------------------ finalize: mean + b2 (one block)
__device__ __forceinline__ int lowerb(const int* __restrict__ a, int n, int key) {
    int lo = 0, hi = n;
    while (lo < hi) { int m = (lo + hi) >> 1; if (a[m] < key) lo = m + 1; else hi = m; }
    return lo;
}

__global__ __launch_bounds__(256) void k_fin(
    const float* __restrict__ accbuf, const int* __restrict__ gid,
    const float* __restrict__ b2, float* __restrict__ out, int nV)
{
    int t = threadIdx.x;          // 256 threads: (g = t>>2, 4 feats each)
    int g = t >> 2, f0 = (t & 3) * 4;
    int lo = lowerb(gid, nV, g);
    int hi = lowerb(gid, nV, g + 1);
    int n = hi - lo;
    float inv = (n > 0) ? 1.f / (float)n : 0.f;
#pragma unroll
    for (int k = 0; k < 4; ++k) {
        int f = f0 + k;
        out[g * 16 + f] = (n > 0) ? accbuf[g * 16 + f] * inv + b2[f] : 0.f;
    }
}

// ----------------------------------------------------------------- launch
extern "C" void kernel_launch(void* const* d_in, const int* in_sizes, int n_in,
                              void* d_out, int out_size, void* d_ws, size_t ws_size,
                              hipStream_t stream) {
    const float* x   = (const float*)d_in[0];
    const float* W1  = (const float*)d_in[1];
    const float* b1  = (const float*)d_in[2];
    const float* W2  = (const float*)d_in[3];
    const float* b2  = (const float*)d_in[4];
    const int*   src = (const int*)d_in[5];
    const int*   dst = (const int*)d_in[6];
    const int*   gid = (const int*)d_in[7];
    float* out = (float*)d_out;

    // ---- workspace layout: fully DISJOINT (23.2 MB) --------------------
    int* p = (int*)d_ws;
    int*   bbaseD  = p;            p += 800;     // uses NBKT+1 = 783
    int*   bbaseS  = p;            p += 800;
    int*   rowptr  = p;            p += 50432;   // uses 50001
    float* rsO     = (float*)p;    p += 50176;
    float* rsI     = (float*)p;    p += 50176;
    unsigned short* csr_src = (unsigned short*)p; p += 400128;  // 800k ushort
    unsigned short* w1f = (unsigned short*)p;     p += 8192;    // 16384 bf16
    unsigned short* w2f = (unsigned short*)p;     p += 1024;    // 2048 bf16
    unsigned short* y   = (unsigned short*)p;     p += 401408;  // 50176*16 bf16
    float* accbuf  = (float*)p;    p += 1024;    // [64][16] graph sums
    unsigned short* xs = (unsigned short*)p;      p += 3211264; // 50176*128 bf16
    int*   hmatD   = p;            p += 153664;  // 196*784
    int*   hmatS   = p;            p += 153664;
    int*   offmatD = p;            p += 153664;
    int*   offmatS = p;            p += 153664;
    unsigned*      ed = (unsigned*)p;      p += 800000;
    unsigned char* es = (unsigned char*)p; p += 200000;

    // ---- CSR build: two-level counting sort, zero global atomics -------
    k_hist <<<NBLK_E, 256, 0, stream>>>(src, dst, hmatD, hmatS, N_EDGES_C);
    k_bscan<<<2, 1024, 0, stream>>>(hmatD, hmatS, bbaseD, bbaseS, accbuf);
    k_boff <<<dim3(NBKT, 2), 256, 0, stream>>>(hmatD, hmatS, bbaseD, bbaseS,
                                               offmatD, offmatS, W1, W2, w1f, w2f);
    k_scat <<<NBLK_E, 256, 0, stream>>>(src, dst, offmatD, offmatS, ed, es, N_EDGES_C);
    k_bucket<<<2 * NBKT, 256, 0, stream>>>(ed, es, bbaseD, bbaseS, x,
                                           rowptr, rsI, rsO, csr_src, xs, N_NODES_C);

    // ---- compute pipeline ---------------------------------------------
    k_fused<<<NBKT, 256, 0, stream>>>(xs, rowptr, csr_src, rsI, b1, w1f, w2f, rsO, y, N_NODES_C);
    k_agg2p<<<(N_NODES_C + 31) / 32, 256, 0, stream>>>(y, rowptr, csr_src, rsI, gid, accbuf, N_NODES_C);
    k_fin  <<<1, 256, 0, stream>>>(accbuf, gid, b2, out, N_NODES_C);
}

// Round 12
// 129.761 us; speedup vs baseline: 1.0276x; 1.0276x over previous
//
#include <hip/hip_runtime.h>
#include <hip/hip_bf16.h>

#define N_NODES_C 50000
#define N_EDGES_C 800000
#define N_GRAPHS_C 64
#define NBKT 782           // buckets of 64 nodes: (50000+63)>>6
#define BKTP 784           // padded bucket count
#define CHUNK 4096         // edges per histogram/scatter block
#define NBLK_E 196         // 196*4096 = 802816 >= 800000

typedef __attribute__((ext_vector_type(8))) short bf16x8;
typedef __attribute__((ext_vector_type(4))) float f32x4;

__device__ __forceinline__ unsigned short f2bf(float f) {
    unsigned u = __float_as_uint(f);
    unsigned r = (u + 0x7FFFu + ((u >> 16) & 1u)) >> 16;   // RNE
    return (unsigned short)r;
}

// ---------------- pass A: per-block LDS histograms over coarse buckets
__global__ __launch_bounds__(256) void k_hist(
    const int* __restrict__ src, const int* __restrict__ dst,
    int* __restrict__ hmatD, int* __restrict__ hmatS, int nE)
{
    __shared__ int hD[BKTP], hS[BKTP];
    const int tid = threadIdx.x, blk = blockIdx.x;
    for (int i = tid; i < BKTP; i += 256) { hD[i] = 0; hS[i] = 0; }
    __syncthreads();
    const int base = blk * CHUNK;
    for (int i = tid; i < CHUNK; i += 256) {
        int e = base + i;
        if (e < nE) {
            atomicAdd(&hD[dst[e] >> 6], 1);
            atomicAdd(&hS[src[e] >> 6], 1);
        }
    }
    __syncthreads();
    for (int i = tid; i < BKTP; i += 256) {
        hmatD[blk * BKTP + i] = hD[i];
        hmatS[blk * BKTP + i] = hS[i];
    }
}

// ------- pass B: bucket totals (coalesced row sums) + scan; zeroes accbuf
__global__ __launch_bounds__(1024) void k_bscan(
    const int* __restrict__ hmatD, const int* __restrict__ hmatS,
    int* __restrict__ bbaseD, int* __restrict__ bbaseS,
    float* __restrict__ accbuf)
{
    __shared__ int part[1024];
    const int tid = threadIdx.x;
    const int* hm = blockIdx.x ? hmatS : hmatD;
    int* bb = blockIdx.x ? bbaseS : bbaseD;
    if (blockIdx.x == 0) accbuf[tid] = 0.f;   // zero [64][16] graph accumulator
    int v = 0;
    if (tid < NBKT)
        for (int blk = 0; blk < NBLK_E; ++blk) v += hm[blk * BKTP + tid];
    part[tid] = v;
    __syncthreads();
    for (int off = 1; off < 1024; off <<= 1) {
        int t = (tid >= off) ? part[tid - off] : 0;
        __syncthreads();
        part[tid] += t;
        __syncthreads();
    }
    if (tid < NBKT) bb[tid] = part[tid] - v;
    if (tid == NBKT - 1) bb[NBKT] = part[tid];
}

// ------- pass B3: per-(bucket,block) scatter offsets (+ w1/w2 frag conv)
__global__ __launch_bounds__(256) void k_boff(
    const int* __restrict__ hmatD, const int* __restrict__ hmatS,
    const int* __restrict__ bbaseD, const int* __restrict__ bbaseS,
    int* __restrict__ offmatD, int* __restrict__ offmatS,
    const float* __restrict__ W1, const float* __restrict__ W2,
    unsigned short* __restrict__ w1f, unsigned short* __restrict__ w2f)
{
    __shared__ int part[256];
    const int b = blockIdx.x, tid = threadIdx.x;
    const int* hm = blockIdx.y ? hmatS : hmatD;
    const int* bb = blockIdx.y ? bbaseS : bbaseD;
    int* om = blockIdx.y ? offmatS : offmatD;
    int v = (tid < NBLK_E) ? hm[tid * BKTP + b] : 0;
    part[tid] = v;
    __syncthreads();
    for (int off = 1; off < 256; off <<= 1) {
        int t = (tid >= off) ? part[tid - off] : 0;
        __syncthreads();
        part[tid] += t;
        __syncthreads();
    }
    if (tid < NBLK_E) om[tid * BKTP + b] = bb[b] + part[tid] - v;

    // side job on 9 spare S-side blocks: W1/W2 -> MFMA B-fragment order
    if (blockIdx.y == 1 && b < 9) {
        int t = b * 256 + tid;
        if (t < 2048) {
            int kk = t >> 9, nt = (t >> 6) & 7, l = t & 63;
            int kb = kk * 32 + ((l >> 4) << 3), n = nt * 16 + (l & 15);
            ushort4 lo, hi;
            lo.x = f2bf(W1[(kb + 0) * 128 + n]); lo.y = f2bf(W1[(kb + 1) * 128 + n]);
            lo.z = f2bf(W1[(kb + 2) * 128 + n]); lo.w = f2bf(W1[(kb + 3) * 128 + n]);
            hi.x = f2bf(W1[(kb + 4) * 128 + n]); hi.y = f2bf(W1[(kb + 5) * 128 + n]);
            hi.z = f2bf(W1[(kb + 6) * 128 + n]); hi.w = f2bf(W1[(kb + 7) * 128 + n]);
            ((ushort4*)(w1f + t * 8))[0] = lo;
            ((ushort4*)(w1f + t * 8))[1] = hi;
        } else if (t < 2304) {
            int t2 = t - 2048;
            int kk = t2 >> 6, l = t2 & 63;
            int kb = kk * 32 + ((l >> 4) << 3), n = l & 15;
            ushort4 lo, hi;
            lo.x = f2bf(W2[(kb + 0) * 16 + n]); lo.y = f2bf(W2[(kb + 1) * 16 + n]);
            lo.z = f2bf(W2[(kb + 2) * 16 + n]); lo.w = f2bf(W2[(kb + 3) * 16 + n]);
            hi.x = f2bf(W2[(kb + 4) * 16 + n]); hi.y = f2bf(W2[(kb + 5) * 16 + n]);
            hi.z = f2bf(W2[(kb + 6) * 16 + n]); hi.w = f2bf(W2[(kb + 7) * 16 + n]);
            ((ushort4*)(w2f + t2 * 8))[0] = lo;
            ((ushort4*)(w2f + t2 * 8))[1] = hi;
        }
    }
}

// ---------------- pass C: scatter edges into buckets (LDS cursors only)
__global__ __launch_bounds__(256) void k_scat(
    const int* __restrict__ src, const int* __restrict__ dst,
    const int* __restrict__ offmatD, const int* __restrict__ offmatS,
    unsigned* __restrict__ ed, unsigned char* __restrict__ es, int nE)
{
    __shared__ int curD[BKTP], curS[BKTP];
    const int tid = threadIdx.x, blk = blockIdx.x;
    for (int i = tid; i < BKTP; i += 256) {
        curD[i] = offmatD[blk * BKTP + i];
        curS[i] = offmatS[blk * BKTP + i];
    }
    __syncthreads();
    const int base = blk * CHUNK;
    for (int i = tid; i < CHUNK; i += 256) {
        int e = base + i;
        if (e < nE) {
            unsigned s = (unsigned)src[e], d = (unsigned)dst[e];
            int pD = atomicAdd(&curD[d >> 6], 1);
            ed[pD] = (d << 16) | s;
            int pS = atomicAdd(&curS[s >> 6], 1);
            es[pS] = (unsigned char)(s & 63u);
        }
    }
}

// ------ pass D: per-bucket finalize (D: rowptr/rsI/csr_src | S: rsO + xs conv)
__global__ __launch_bounds__(256) void k_bucket(
    const unsigned* __restrict__ ed, const unsigned char* __restrict__ es,
    const int* __restrict__ bbaseD, const int* __restrict__ bbaseS,
    const float* __restrict__ x,
    int* __restrict__ rowptr, float* __restrict__ rsI, float* __restrict__ rsO,
    unsigned short* __restrict__ csr_src, unsigned short* __restrict__ xs, int nV)
{
    __shared__ int cnt[64], cur[64];
    __shared__ float rs[64];
    const int tid = threadIdx.x;
    const int side = (blockIdx.x >= NBKT);
    const int b = side ? blockIdx.x - NBKT : blockIdx.x;

    if (tid < 64) cnt[tid] = 0;
    __syncthreads();

    if (!side) {
        const int lo = bbaseD[b], hi = bbaseD[b + 1];
        for (int j = lo + tid; j < hi; j += 256)
            atomicAdd(&cnt[(ed[j] >> 16) & 63u], 1);
        __syncthreads();
        if (tid < 64) {
            int c = cnt[tid];
            int v = c;
#pragma unroll
            for (int off = 1; off < 64; off <<= 1) {
                int n = __shfl_up(v, off, 64);
                if (tid >= off) v += n;
            }
            int excl = v - c;
            int node = b * 64 + tid;
            if (node <= nV) rowptr[node] = lo + excl;
            if (node < nV) rsI[node] = rsqrtf((float)max(c, 1));
            cur[tid] = excl;
        }
        __syncthreads();
        for (int j = lo + tid; j < hi; j += 256) {
            unsigned v = ed[j];
            int p = atomicAdd(&cur[(v >> 16) & 63u], 1);
            csr_src[lo + p] = (unsigned short)(v & 0xFFFFu);
        }
    } else {
        const int lo = bbaseS[b], hi = bbaseS[b + 1];
        for (int j = lo + tid; j < hi; j += 256)
            atomicAdd(&cnt[es[j]], 1);
        __syncthreads();
        if (tid < 64) {
            int node = b * 64 + tid;
            float r = rsqrtf((float)max(cnt[tid], 1));
            if (node < nV) rsO[node] = r;
            rs[tid] = r;
        }
        __syncthreads();
        // convert this bucket's 64 rows: xs = bf16(x * rsO)
        for (int q = tid; q < 64 * 32; q += 256) {
            int n = q >> 5, c = q & 31;
            int node = b * 64 + n;
            if (node < nV) {
                float wgt = rs[n];
                float4 a = ((const float4*)(x + (size_t)node * 128))[c];
                ushort4 o;
                o.x = f2bf(a.x * wgt); o.y = f2bf(a.y * wgt);
                o.z = f2bf(a.z * wgt); o.w = f2bf(a.w * wgt);
                ((ushort4*)(xs + (size_t)node * 128))[c] = o;
            }
        }
    }
}

#define ACC8(vv)                                         \
    acc[0] += __uint_as_float((vv).x << 16);             \
    acc[1] += __uint_as_float((vv).x & 0xFFFF0000u);     \
    acc[2] += __uint_as_float((vv).y << 16);             \
    acc[3] += __uint_as_float((vv).y & 0xFFFF0000u);     \
    acc[4] += __uint_as_float((vv).z << 16);             \
    acc[5] += __uint_as_float((vv).z & 0xFFFF0000u);     \
    acc[6] += __uint_as_float((vv).w << 16);             \
    acc[7] += __uint_as_float((vv).w & 0xFFFF0000u);

// ---- fused: gather-to-LDS + MFMA layer1 + relu + MFMA layer2 -> y (bf16)
// 1563 blocks x 4 waves; 32-row tile/block; each wave gathers 8 rows (2x TLP
// vs R10's 16). Wave-pair {2t,2t+1} shares 16-row MFMA tile t: each wave does
// 4 of the 8 layer-1 nt-blocks (disjoint LDS writes); even wave does layer-2.
__global__ __launch_bounds__(256) void k_fused(
    const unsigned short* __restrict__ xs, const int* __restrict__ rowptr,
    const unsigned short* __restrict__ csr_src, const float* __restrict__ rsI,
    const float* __restrict__ b1, const unsigned short* __restrict__ w1f,
    const unsigned short* __restrict__ w2f, const float* __restrict__ rsO,
    unsigned short* __restrict__ y, int nV)
{
    __shared__ __align__(16) unsigned short Al[32 * 136];   // padded rows (272 B)
    const int tid = threadIdx.x;
    const int w = tid >> 6, l = tid & 63;
    const int g = l >> 4, fl = l & 15;        // 4 edge-groups x 16 feature-lanes
    const int row0 = blockIdx.x * 32;

    // ---- phase A: gather 8 rows (agg1 = rsI * sum xs[src]) into LDS
    for (int n = 0; n < 8; ++n) {
        int r = w * 8 + n;
        int v = row0 + r;
        float acc[8];
#pragma unroll
        for (int k = 0; k < 8; ++k) acc[k] = 0.f;
        float ri = 0.f;
        if (v < nV) {
            ri = rsI[v];
            int beg = rowptr[v], end = rowptr[v + 1];
            int j = beg + g;
            while (j + 12 < end) {
                int s0 = csr_src[j], s1 = csr_src[j + 4], s2 = csr_src[j + 8], s3 = csr_src[j + 12];
                uint4 w0 = *(const uint4*)(xs + (size_t)s0 * 128 + fl * 8);
                uint4 w1 = *(const uint4*)(xs + (size_t)s1 * 128 + fl * 8);
                uint4 w2 = *(const uint4*)(xs + (size_t)s2 * 128 + fl * 8);
                uint4 w3 = *(const uint4*)(xs + (size_t)s3 * 128 + fl * 8);
                ACC8(w0); ACC8(w1); ACC8(w2); ACC8(w3);
                j += 16;
            }
            while (j + 4 < end) {
                int s0 = csr_src[j], s1 = csr_src[j + 4];
                uint4 w0 = *(const uint4*)(xs + (size_t)s0 * 128 + fl * 8);
                uint4 w1 = *(const uint4*)(xs + (size_t)s1 * 128 + fl * 8);
                ACC8(w0); ACC8(w1);
                j += 8;
            }
            if (j < end) {
                int s0 = csr_src[j];
                uint4 w0 = *(const uint4*)(xs + (size_t)s0 * 128 + fl * 8);
                ACC8(w0);
            }
        }
#pragma unroll
        for (int k = 0; k < 8; ++k) {
            acc[k] += __shfl_xor(acc[k], 16, 64);
            acc[k] += __shfl_xor(acc[k], 32, 64);
        }
        if (g < 2) {
            ushort4 o;
            o.x = f2bf(acc[g * 4 + 0] * ri);
            o.y = f2bf(acc[g * 4 + 1] * ri);
            o.z = f2bf(acc[g * 4 + 2] * ri);
            o.w = f2bf(acc[g * 4 + 3] * ri);
            *(ushort4*)(&Al[r * 136 + fl * 8 + g * 4]) = o;
        }
    }
    __syncthreads();

    // ---- phase B: layer-1 MFMA; wave-pair splits the 8 nt-blocks
    const int t = w >> 1, half = w & 1;       // tile t in {0,1}, nt range
    const int lr = fl, lg = g;
    bf16x8 a[4];
#pragma unroll
    for (int kk = 0; kk < 4; ++kk)
        a[kk] = *(const bf16x8*)(&Al[(t * 16 + lr) * 136 + kk * 32 + lg * 8]);

    f32x4 acc1[4];
#pragma unroll
    for (int q = 0; q < 4; ++q) acc1[q] = (f32x4){0.f, 0.f, 0.f, 0.f};
#pragma unroll
    for (int q = 0; q < 4; ++q) {
        int nt = half * 4 + q;
#pragma unroll
        for (int kk = 0; kk < 4; ++kk) {
            bf16x8 b = *(const bf16x8*)(w1f + ((kk * 8 + nt) * 64 + l) * 8);
            acc1[q] = __builtin_amdgcn_mfma_f32_16x16x32_bf16(a[kk], b, acc1[q], 0, 0, 0);
        }
    }

    // epilogue 1: +b1, relu, bf16 -> back into Al (disjoint col ranges per wave)
#pragma unroll
    for (int q = 0; q < 4; ++q) {
        int nt = half * 4 + q;
        float bb = b1[nt * 16 + lr];
#pragma unroll
        for (int i = 0; i < 4; ++i) {
            float h = fmaxf(acc1[q][i] + bb, 0.f);
            Al[(t * 16 + lg * 4 + i) * 136 + nt * 16 + lr] = f2bf(h);
        }
    }
    __syncthreads();

    // ---- phase C: layer-2 MFMA (even wave of each pair), y = (h1@W2)*rsO
    if (half == 0) {
        f32x4 acc2 = (f32x4){0.f, 0.f, 0.f, 0.f};
#pragma unroll
        for (int kk = 0; kk < 4; ++kk) {
            bf16x8 a2 = *(const bf16x8*)(&Al[(t * 16 + lr) * 136 + kk * 32 + lg * 8]);
            bf16x8 b2 = *(const bf16x8*)(w2f + (kk * 64 + l) * 8);
            acc2 = __builtin_amdgcn_mfma_f32_16x16x32_bf16(a2, b2, acc2, 0, 0, 0);
        }
#pragma unroll
        for (int i = 0; i < 4; ++i) {
            int r = row0 + t * 16 + lg * 4 + i;
            if (r < nV) y[(size_t)r * 16 + lr] = f2bf(acc2[i] * rsO[r]);
        }
    }
}

// --------- fused layer-2 agg + rsI scale + per-graph pooling
__global__ __launch_bounds__(256) void k_agg2p(
    const unsigned short* __restrict__ y, const int* __restrict__ rowptr,
    const unsigned short* __restrict__ csr_src, const float* __restrict__ rsI,
    const int* __restrict__ gid, float* __restrict__ accbuf, int nV)
{
    const int tid = threadIdx.x;
    const int lane = tid & 63, f = lane & 15, g4 = lane >> 4;
    const int wid = blockIdx.x * 4 + (tid >> 6);
    int v0 = wid * 8;
    if (v0 >= nV) return;
    int vend = min(v0 + 8, nV);
    float racc = 0.f;
    int curg = gid[v0];
    for (int v = v0; v < vend; ++v) {
        int beg = rowptr[v], end = rowptr[v + 1];
        float acc = 0.f;
        int j = beg + g4;
        while (j + 4 < end) {
            int s0 = csr_src[j], s1 = csr_src[j + 4];
            unsigned u0 = y[(size_t)s0 * 16 + f];
            unsigned u1 = y[(size_t)s1 * 16 + f];
            acc += __uint_as_float(u0 << 16) + __uint_as_float(u1 << 16);
            j += 8;
        }
        if (j < end) {
            unsigned u = y[(size_t)csr_src[j] * 16 + f];
            acc += __uint_as_float(u << 16);
        }
        acc += __shfl_xor(acc, 16, 64);
        acc += __shfl_xor(acc, 32, 64);
        int gg = gid[v];
        if (gg != curg) {
            if (g4 == 0 && racc != 0.f) unsafeAtomicAdd(&accbuf[curg * 16 + f], racc);
            racc = 0.f;
            curg = gg;
        }
        racc += acc * rsI[v];
    }
    if (g4 == 0 && racc != 0.f) unsafeAtomicAdd(&accbuf[curg * 16 + f], racc);
}

// ------------------------------------------ finalize: mean + b2 (one block)
__device__ __forceinline__ int lowerb(const int* __restrict__ a, int n, int key) {
    int lo = 0, hi = n;
    while (lo < hi) { int m = (lo + hi) >> 1; if (a[m] < key) lo = m + 1; else hi = m; }
    return lo;
}

__global__ __launch_bounds__(256) void k_fin(
    const float* __restrict__ accbuf, const int* __restrict__ gid,
    const float* __restrict__ b2, float* __restrict__ out, int nV)
{
    int t = threadIdx.x;          // 256 threads: (g = t>>2, 4 feats each)
    int g = t >> 2, f0 = (t & 3) * 4;
    int lo = lowerb(gid, nV, g);
    int hi = lowerb(gid, nV, g + 1);
    int n = hi - lo;
    float inv = (n > 0) ? 1.f / (float)n : 0.f;
#pragma unroll
    for (int k = 0; k < 4; ++k) {
        int f = f0 + k;
        out[g * 16 + f] = (n > 0) ? accbuf[g * 16 + f] * inv + b2[f] : 0.f;
    }
}

// ----------------------------------------------------------------- launch
extern "C" void kernel_launch(void* const* d_in, const int* in_sizes, int n_in,
                              void* d_out, int out_size, void* d_ws, size_t ws_size,
                              hipStream_t stream) {
    const float* x   = (const float*)d_in[0];
    const float* W1  = (const float*)d_in[1];
    const float* b1  = (const float*)d_in[2];
    const float* W2  = (const float*)d_in[3];
    const float* b2  = (const float*)d_in[4];
    const int*   src = (const int*)d_in[5];
    const int*   dst = (const int*)d_in[6];
    const int*   gid = (const int*)d_in[7];
    float* out = (float*)d_out;

    // ---- workspace layout: fully DISJOINT (23.2 MB) --------------------
    int* p = (int*)d_ws;
    int*   bbaseD  = p;            p += 800;     // uses NBKT+1 = 783
    int*   bbaseS  = p;            p += 800;
    int*   rowptr  = p;            p += 50432;   // uses 50001
    float* rsO     = (float*)p;    p += 50176;
    float* rsI     = (float*)p;    p += 50176;
    unsigned short* csr_src = (unsigned short*)p; p += 400128;  // 800k ushort
    unsigned short* w1f = (unsigned short*)p;     p += 8192;    // 16384 bf16
    unsigned short* w2f = (unsigned short*)p;     p += 1024;    // 2048 bf16
    unsigned short* y   = (unsigned short*)p;     p += 401408;  // 50176*16 bf16
    float* accbuf  = (float*)p;    p += 1024;    // [64][16] graph sums
    unsigned short* xs = (unsigned short*)p;      p += 3211264; // 50176*128 bf16
    int*   hmatD   = p;            p += 153664;  // 196*784
    int*   hmatS   = p;            p += 153664;
    int*   offmatD = p;            p += 153664;
    int*   offmatS = p;            p += 153664;
    unsigned*      ed = (unsigned*)p;      p += 800000;
    unsigned char* es = (unsigned char*)p; p += 200000;

    // ---- CSR build: two-level counting sort, zero global atomics -------
    k_hist <<<NBLK_E, 256, 0, stream>>>(src, dst, hmatD, hmatS, N_EDGES_C);
    k_bscan<<<2, 1024, 0, stream>>>(hmatD, hmatS, bbaseD, bbaseS, accbuf);
    k_boff <<<dim3(NBKT, 2), 256, 0, stream>>>(hmatD, hmatS, bbaseD, bbaseS,
                                               offmatD, offmatS, W1, W2, w1f, w2f);
    k_scat <<<NBLK_E, 256, 0, stream>>>(src, dst, offmatD, offmatS, ed, es, N_EDGES_C);
    k_bucket<<<2 * NBKT, 256, 0, stream>>>(ed, es, bbaseD, bbaseS, x,
                                           rowptr, rsI, rsO, csr_src, xs, N_NODES_C);

    // ---- compute pipeline ---------------------------------------------
    k_fused<<<(N_NODES_C + 31) / 32, 256, 0, stream>>>(xs, rowptr, csr_src, rsI, b1, w1f, w2f, rsO, y, N_NODES_C);
    k_agg2p<<<(N_NODES_C + 31) / 32, 256, 0, stream>>>(y, rowptr, csr_src, rsI, gid, accbuf, N_NODES_C);
    k_fin  <<<1, 256, 0, stream>>>(accbuf, gid, b2, out, N_NODES_C);
}

// Round 13
// 124.272 us; speedup vs baseline: 1.0729x; 1.0442x over previous
//
#include <hip/hip_runtime.h>
#include <hip/hip_bf16.h>

#define N_NODES_C 50000
#define N_EDGES_C 800000
#define N_GRAPHS_C 64
#define NBKT 782           // buckets of 64 nodes: (50000+63)>>6
#define BKTP 784           // padded bucket count
#define CHUNK 4096         // edges per histogram/scatter block
#define NBLK_E 196         // 196*4096 = 802816 >= 800000

typedef __attribute__((ext_vector_type(8))) short bf16x8;
typedef __attribute__((ext_vector_type(4))) float f32x4;

__device__ __forceinline__ unsigned short f2bf(float f) {
    unsigned u = __float_as_uint(f);
    unsigned r = (u + 0x7FFFu + ((u >> 16) & 1u)) >> 16;   // RNE
    return (unsigned short)r;
}

// ---------------- pass A: per-block LDS histograms over coarse buckets
__global__ __launch_bounds__(256) void k_hist(
    const int* __restrict__ src, const int* __restrict__ dst,
    int* __restrict__ hmatD, int* __restrict__ hmatS, int nE)
{
    __shared__ int hD[BKTP], hS[BKTP];
    const int tid = threadIdx.x, blk = blockIdx.x;
    for (int i = tid; i < BKTP; i += 256) { hD[i] = 0; hS[i] = 0; }
    __syncthreads();
    const int base = blk * CHUNK;
    for (int i = tid; i < CHUNK; i += 256) {
        int e = base + i;
        if (e < nE) {
            atomicAdd(&hD[dst[e] >> 6], 1);
            atomicAdd(&hS[src[e] >> 6], 1);
        }
    }
    __syncthreads();
    for (int i = tid; i < BKTP; i += 256) {
        hmatD[blk * BKTP + i] = hD[i];
        hmatS[blk * BKTP + i] = hS[i];
    }
}

// ------- pass B: bucket totals (coalesced row sums) + scan; zeroes accbuf
__global__ __launch_bounds__(1024) void k_bscan(
    const int* __restrict__ hmatD, const int* __restrict__ hmatS,
    int* __restrict__ bbaseD, int* __restrict__ bbaseS,
    float* __restrict__ accbuf)
{
    __shared__ int part[1024];
    const int tid = threadIdx.x;
    const int* hm = blockIdx.x ? hmatS : hmatD;
    int* bb = blockIdx.x ? bbaseS : bbaseD;
    if (blockIdx.x == 0) accbuf[tid] = 0.f;   // zero [64][16] graph accumulator
    int v = 0;
    if (tid < NBKT)
        for (int blk = 0; blk < NBLK_E; ++blk) v += hm[blk * BKTP + tid];
    part[tid] = v;
    __syncthreads();
    for (int off = 1; off < 1024; off <<= 1) {
        int t = (tid >= off) ? part[tid - off] : 0;
        __syncthreads();
        part[tid] += t;
        __syncthreads();
    }
    if (tid < NBKT) bb[tid] = part[tid] - v;
    if (tid == NBKT - 1) bb[NBKT] = part[tid];
}

// ------- pass B3: per-(bucket,block) scatter offsets (+ w1/w2 frag conv)
__global__ __launch_bounds__(256) void k_boff(
    const int* __restrict__ hmatD, const int* __restrict__ hmatS,
    const int* __restrict__ bbaseD, const int* __restrict__ bbaseS,
    int* __restrict__ offmatD, int* __restrict__ offmatS,
    const float* __restrict__ W1, const float* __restrict__ W2,
    unsigned short* __restrict__ w1f, unsigned short* __restrict__ w2f)
{
    __shared__ int part[256];
    const int b = blockIdx.x, tid = threadIdx.x;
    const int* hm = blockIdx.y ? hmatS : hmatD;
    const int* bb = blockIdx.y ? bbaseS : bbaseD;
    int* om = blockIdx.y ? offmatS : offmatD;
    int v = (tid < NBLK_E) ? hm[tid * BKTP + b] : 0;
    part[tid] = v;
    __syncthreads();
    for (int off = 1; off < 256; off <<= 1) {
        int t = (tid >= off) ? part[tid - off] : 0;
        __syncthreads();
        part[tid] += t;
        __syncthreads();
    }
    if (tid < NBLK_E) om[tid * BKTP + b] = bb[b] + part[tid] - v;

    // side job on 9 spare S-side blocks: W1/W2 -> MFMA B-fragment order
    if (blockIdx.y == 1 && b < 9) {
        int t = b * 256 + tid;
        if (t < 2048) {
            int kk = t >> 9, nt = (t >> 6) & 7, l = t & 63;
            int kb = kk * 32 + ((l >> 4) << 3), n = nt * 16 + (l & 15);
            ushort4 lo, hi;
            lo.x = f2bf(W1[(kb + 0) * 128 + n]); lo.y = f2bf(W1[(kb + 1) * 128 + n]);
            lo.z = f2bf(W1[(kb + 2) * 128 + n]); lo.w = f2bf(W1[(kb + 3) * 128 + n]);
            hi.x = f2bf(W1[(kb + 4) * 128 + n]); hi.y = f2bf(W1[(kb + 5) * 128 + n]);
            hi.z = f2bf(W1[(kb + 6) * 128 + n]); hi.w = f2bf(W1[(kb + 7) * 128 + n]);
            ((ushort4*)(w1f + t * 8))[0] = lo;
            ((ushort4*)(w1f + t * 8))[1] = hi;
        } else if (t < 2304) {
            int t2 = t - 2048;
            int kk = t2 >> 6, l = t2 & 63;
            int kb = kk * 32 + ((l >> 4) << 3), n = l & 15;
            ushort4 lo, hi;
            lo.x = f2bf(W2[(kb + 0) * 16 + n]); lo.y = f2bf(W2[(kb + 1) * 16 + n]);
            lo.z = f2bf(W2[(kb + 2) * 16 + n]); lo.w = f2bf(W2[(kb + 3) * 16 + n]);
            hi.x = f2bf(W2[(kb + 4) * 16 + n]); hi.y = f2bf(W2[(kb + 5) * 16 + n]);
            hi.z = f2bf(W2[(kb + 6) * 16 + n]); hi.w = f2bf(W2[(kb + 7) * 16 + n]);
            ((ushort4*)(w2f + t2 * 8))[0] = lo;
            ((ushort4*)(w2f + t2 * 8))[1] = hi;
        }
    }
}

// ---------------- pass C: scatter edges into buckets (LDS cursors only)
__global__ __launch_bounds__(256) void k_scat(
    const int* __restrict__ src, const int* __restrict__ dst,
    const int* __restrict__ offmatD, const int* __restrict__ offmatS,
    unsigned* __restrict__ ed, unsigned char* __restrict__ es, int nE)
{
    __shared__ int curD[BKTP], curS[BKTP];
    const int tid = threadIdx.x, blk = blockIdx.x;
    for (int i = tid; i < BKTP; i += 256) {
        curD[i] = offmatD[blk * BKTP + i];
        curS[i] = offmatS[blk * BKTP + i];
    }
    __syncthreads();
    const int base = blk * CHUNK;
    for (int i = tid; i < CHUNK; i += 256) {
        int e = base + i;
        if (e < nE) {
            unsigned s = (unsigned)src[e], d = (unsigned)dst[e];
            int pD = atomicAdd(&curD[d >> 6], 1);
            ed[pD] = (d << 16) | s;
            int pS = atomicAdd(&curS[s >> 6], 1);
            es[pS] = (unsigned char)(s & 63u);
        }
    }
}

// ------ pass D: per-bucket finalize (D: rowptr/rsI/csr_src | S: rsO + xs conv)
__global__ __launch_bounds__(256) void k_bucket(
    const unsigned* __restrict__ ed, const unsigned char* __restrict__ es,
    const int* __restrict__ bbaseD, const int* __restrict__ bbaseS,
    const float* __restrict__ x,
    int* __restrict__ rowptr, float* __restrict__ rsI, float* __restrict__ rsO,
    unsigned short* __restrict__ csr_src, unsigned short* __restrict__ xs, int nV)
{
    __shared__ int cnt[64], cur[64];
    __shared__ float rs[64];
    const int tid = threadIdx.x;
    const int side = (blockIdx.x >= NBKT);
    const int b = side ? blockIdx.x - NBKT : blockIdx.x;

    if (tid < 64) cnt[tid] = 0;
    __syncthreads();

    if (!side) {
        const int lo = bbaseD[b], hi = bbaseD[b + 1];
        for (int j = lo + tid; j < hi; j += 256)
            atomicAdd(&cnt[(ed[j] >> 16) & 63u], 1);
        __syncthreads();
        if (tid < 64) {
            int c = cnt[tid];
            int v = c;
#pragma unroll
            for (int off = 1; off < 64; off <<= 1) {
                int n = __shfl_up(v, off, 64);
                if (tid >= off) v += n;
            }
            int excl = v - c;
            int node = b * 64 + tid;
            if (node <= nV) rowptr[node] = lo + excl;
            if (node < nV) rsI[node] = rsqrtf((float)max(c, 1));
            cur[tid] = excl;
        }
        __syncthreads();
        for (int j = lo + tid; j < hi; j += 256) {
            unsigned v = ed[j];
            int p = atomicAdd(&cur[(v >> 16) & 63u], 1);
            csr_src[lo + p] = (unsigned short)(v & 0xFFFFu);
        }
    } else {
        const int lo = bbaseS[b], hi = bbaseS[b + 1];
        for (int j = lo + tid; j < hi; j += 256)
            atomicAdd(&cnt[es[j]], 1);
        __syncthreads();
        if (tid < 64) {
            int node = b * 64 + tid;
            float r = rsqrtf((float)max(cnt[tid], 1));
            if (node < nV) rsO[node] = r;
            rs[tid] = r;
        }
        __syncthreads();
        // convert this bucket's 64 rows: xs = bf16(x * rsO)
        for (int q = tid; q < 64 * 32; q += 256) {
            int n = q >> 5, c = q & 31;
            int node = b * 64 + n;
            if (node < nV) {
                float wgt = rs[n];
                float4 a = ((const float4*)(x + (size_t)node * 128))[c];
                ushort4 o;
                o.x = f2bf(a.x * wgt); o.y = f2bf(a.y * wgt);
                o.z = f2bf(a.z * wgt); o.w = f2bf(a.w * wgt);
                ((ushort4*)(xs + (size_t)node * 128))[c] = o;
            }
        }
    }
}

#define ACC8(vv)                                         \
    acc[0] += __uint_as_float((vv).x << 16);             \
    acc[1] += __uint_as_float((vv).x & 0xFFFF0000u);     \
    acc[2] += __uint_as_float((vv).y << 16);             \
    acc[3] += __uint_as_float((vv).y & 0xFFFF0000u);     \
    acc[4] += __uint_as_float((vv).z << 16);             \
    acc[5] += __uint_as_float((vv).z & 0xFFFF0000u);     \
    acc[6] += __uint_as_float((vv).w << 16);             \
    acc[7] += __uint_as_float((vv).w & 0xFFFF0000u);

// ---------------- layer-1 aggregation (bf16 gather, 4-deep ILP unroll)
__global__ __launch_bounds__(256) void k_agg1b(
    const unsigned short* __restrict__ xs, const int* __restrict__ rowptr,
    const unsigned short* __restrict__ csr_src, const float* __restrict__ rsI,
    unsigned short* __restrict__ agg1b, int nV)
{
    long long t = (long long)blockIdx.x * blockDim.x + threadIdx.x;
    int v = (int)(t >> 6);
    int lane = (int)(t & 63);
    if (v >= nV) return;
    int g = lane >> 4, fl = lane & 15;
    int beg = rowptr[v], end = rowptr[v + 1];
    float acc[8];
#pragma unroll
    for (int k = 0; k < 8; ++k) acc[k] = 0.f;

    int j = beg + g;
    while (j + 12 < end) {
        int s0 = csr_src[j], s1 = csr_src[j + 4], s2 = csr_src[j + 8], s3 = csr_src[j + 12];
        uint4 w0 = *(const uint4*)(xs + (size_t)s0 * 128 + fl * 8);
        uint4 w1 = *(const uint4*)(xs + (size_t)s1 * 128 + fl * 8);
        uint4 w2 = *(const uint4*)(xs + (size_t)s2 * 128 + fl * 8);
        uint4 w3 = *(const uint4*)(xs + (size_t)s3 * 128 + fl * 8);
        ACC8(w0); ACC8(w1); ACC8(w2); ACC8(w3);
        j += 16;
    }
    while (j + 4 < end) {
        int s0 = csr_src[j], s1 = csr_src[j + 4];
        uint4 w0 = *(const uint4*)(xs + (size_t)s0 * 128 + fl * 8);
        uint4 w1 = *(const uint4*)(xs + (size_t)s1 * 128 + fl * 8);
        ACC8(w0); ACC8(w1);
        j += 8;
    }
    if (j < end) {
        int s = csr_src[j];
        uint4 w0 = *(const uint4*)(xs + (size_t)s * 128 + fl * 8);
        ACC8(w0);
    }
#pragma unroll
    for (int k = 0; k < 8; ++k) {
        acc[k] += __shfl_xor(acc[k], 16, 64);
        acc[k] += __shfl_xor(acc[k], 32, 64);
    }
    float ri = rsI[v];
    if (g < 2) {
        ushort4 o;
        o.x = f2bf(acc[g * 4 + 0] * ri);
        o.y = f2bf(acc[g * 4 + 1] * ri);
        o.z = f2bf(acc[g * 4 + 2] * ri);
        o.w = f2bf(acc[g * 4 + 3] * ri);
        *(ushort4*)(agg1b + (size_t)v * 128 + fl * 8 + g * 4) = o;
    }
}

// -------------------- fused MFMA GEMMs: h1 = relu(agg1b@W1+b1); y = (h1@W2)*rsO
__global__ __launch_bounds__(256) void k_mfma(
    const unsigned short* __restrict__ agg1b, const float* __restrict__ b1,
    const unsigned short* __restrict__ w1f, const unsigned short* __restrict__ w2f,
    const float* __restrict__ rsO, unsigned short* __restrict__ y, int nV)
{
    __shared__ __align__(16) unsigned short h1[64 * 136];
    const int tid = threadIdx.x;
    const int w = tid >> 6, l = tid & 63;
    const int lr = l & 15, lg = l >> 4;
    const int row0 = blockIdx.x * 64;

    bf16x8 a[4];
    const unsigned short* abase = agg1b + (size_t)(row0 + w * 16 + lr) * 128 + lg * 8;
#pragma unroll
    for (int kk = 0; kk < 4; ++kk)
        a[kk] = *(const bf16x8*)(abase + kk * 32);

    f32x4 acc[8];
#pragma unroll
    for (int nt = 0; nt < 8; ++nt) acc[nt] = (f32x4){0.f, 0.f, 0.f, 0.f};

#pragma unroll
    for (int nt = 0; nt < 8; ++nt)
#pragma unroll
        for (int kk = 0; kk < 4; ++kk) {
            bf16x8 b = *(const bf16x8*)(w1f + ((kk * 8 + nt) * 64 + l) * 8);
            acc[nt] = __builtin_amdgcn_mfma_f32_16x16x32_bf16(a[kk], b, acc[nt], 0, 0, 0);
        }

#pragma unroll
    for (int nt = 0; nt < 8; ++nt) {
        float bb = b1[nt * 16 + lr];
#pragma unroll
        for (int i = 0; i < 4; ++i) {
            float h = fmaxf(acc[nt][i] + bb, 0.f);
            h1[(w * 16 + lg * 4 + i) * 136 + nt * 16 + lr] = f2bf(h);
        }
    }
    __syncthreads();

    f32x4 acc2 = (f32x4){0.f, 0.f, 0.f, 0.f};
#pragma unroll
    for (int kk = 0; kk < 4; ++kk) {
        bf16x8 a2 = *(const bf16x8*)(&h1[(w * 16 + lr) * 136 + kk * 32 + lg * 8]);
        bf16x8 b2 = *(const bf16x8*)(w2f + (kk * 64 + l) * 8);
        acc2 = __builtin_amdgcn_mfma_f32_16x16x32_bf16(a2, b2, acc2, 0, 0, 0);
    }
#pragma unroll
    for (int i = 0; i < 4; ++i) {
        int r = row0 + w * 16 + lg * 4 + i;
        if (r < nV) y[(size_t)r * 16 + lr] = f2bf(acc2[i] * rsO[r]);
    }
}

// --------- fused layer-2 agg + rsI scale + per-graph pooling
__global__ __launch_bounds__(256) void k_agg2p(
    const unsigned short* __restrict__ y, const int* __restrict__ rowptr,
    const unsigned short* __restrict__ csr_src, const float* __restrict__ rsI,
    const int* __restrict__ gid, float* __restrict__ accbuf, int nV)
{
    const int tid = threadIdx.x;
    const int lane = tid & 63, f = lane & 15, g4 = lane >> 4;
    const int wid = blockIdx.x * 4 + (tid >> 6);
    int v0 = wid * 8;
    if (v0 >= nV) return;
    int vend = min(v0 + 8, nV);
    float racc = 0.f;
    int curg = gid[v0];
    for (int v = v0; v < vend; ++v) {
        int beg = rowptr[v], end = rowptr[v + 1];
        float acc = 0.f;
        int j = beg + g4;
        while (j + 4 < end) {
            int s0 = csr_src[j], s1 = csr_src[j + 4];
            unsigned u0 = y[(size_t)s0 * 16 + f];
            unsigned u1 = y[(size_t)s1 * 16 + f];
            acc += __uint_as_float(u0 << 16) + __uint_as_float(u1 << 16);
            j += 8;
        }
        if (j < end) {
            unsigned u = y[(size_t)csr_src[j] * 16 + f];
            acc += __uint_as_float(u << 16);
        }
        acc += __shfl_xor(acc, 16, 64);
        acc += __shfl_xor(acc, 32, 64);
        int gg = gid[v];
        if (gg != curg) {
            if (g4 == 0 && racc != 0.f) unsafeAtomicAdd(&accbuf[curg * 16 + f], racc);
            racc = 0.f;
            curg = gg;
        }
        racc += acc * rsI[v];
    }
    if (g4 == 0 && racc != 0.f) unsafeAtomicAdd(&accbuf[curg * 16 + f], racc);
}

// ------------------------------------------ finalize: mean + b2 (one block)
__device__ __forceinline__ int lowerb(const int* __restrict__ a, int n, int key) {
    int lo = 0, hi = n;
    while (lo < hi) { int m = (lo + hi) >> 1; if (a[m] < key) lo = m + 1; else hi = m; }
    return lo;
}

__global__ __launch_bounds__(256) void k_fin(
    const float* __restrict__ accbuf, const int* __restrict__ gid,
    const float* __restrict__ b2, float* __restrict__ out, int nV)
{
    int t = threadIdx.x;          // 256 threads: (g = t>>2, 4 feats each)
    int g = t >> 2, f0 = (t & 3) * 4;
    int lo = lowerb(gid, nV, g);
    int hi = lowerb(gid, nV, g + 1);
    int n = hi - lo;
    float inv = (n > 0) ? 1.f / (float)n : 0.f;
#pragma unroll
    for (int k = 0; k < 4; ++k) {
        int f = f0 + k;
        out[g * 16 + f] = (n > 0) ? accbuf[g * 16 + f] * inv + b2[f] : 0.f;
    }
}

// ----------------------------------------------------------------- launch
extern "C" void kernel_launch(void* const* d_in, const int* in_sizes, int n_in,
                              void* d_out, int out_size, void* d_ws, size_t ws_size,
                              hipStream_t stream) {
    const float* x   = (const float*)d_in[0];
    const float* W1  = (const float*)d_in[1];
    const float* b1  = (const float*)d_in[2];
    const float* W2  = (const float*)d_in[3];
    const float* b2  = (const float*)d_in[4];
    const int*   src = (const int*)d_in[5];
    const int*   dst = (const int*)d_in[6];
    const int*   gid = (const int*)d_in[7];
    float* out = (float*)d_out;

    // ---- workspace layout: fully DISJOINT (~36.0 MB) -------------------
    int* p = (int*)d_ws;
    int*   bbaseD  = p;            p += 800;     // uses NBKT+1 = 783
    int*   bbaseS  = p;            p += 800;
    int*   rowptr  = p;            p += 50432;   // uses 50001
    float* rsO     = (float*)p;    p += 50176;
    float* rsI     = (float*)p;    p += 50176;
    unsigned short* csr_src = (unsigned short*)p; p += 400128;  // 800k ushort
    unsigned short* w1f = (unsigned short*)p;     p += 8192;    // 16384 bf16
    unsigned short* w2f = (unsigned short*)p;     p += 1024;    // 2048 bf16
    unsigned short* y   = (unsigned short*)p;     p += 401408;  // 50176*16 bf16
    float* accbuf  = (float*)p;    p += 1024;    // [64][16] graph sums
    unsigned short* xs    = (unsigned short*)p;   p += 3211264; // 50176*128 bf16
    unsigned short* agg1b = (unsigned short*)p;   p += 3211264; // 50176*128 bf16
    int*   hmatD   = p;            p += 153664;  // 196*784
    int*   hmatS   = p;            p += 153664;
    int*   offmatD = p;            p += 153664;
    int*   offmatS = p;            p += 153664;
    unsigned*      ed = (unsigned*)p;      p += 800000;
    unsigned char* es = (unsigned char*)p; p += 200000;

    // ---- CSR build: two-level counting sort, zero global atomics -------
    k_hist <<<NBLK_E, 256, 0, stream>>>(src, dst, hmatD, hmatS, N_EDGES_C);
    k_bscan<<<2, 1024, 0, stream>>>(hmatD, hmatS, bbaseD, bbaseS, accbuf);
    k_boff <<<dim3(NBKT, 2), 256, 0, stream>>>(hmatD, hmatS, bbaseD, bbaseS,
                                               offmatD, offmatS, W1, W2, w1f, w2f);
    k_scat <<<NBLK_E, 256, 0, stream>>>(src, dst, offmatD, offmatS, ed, es, N_EDGES_C);
    k_bucket<<<2 * NBKT, 256, 0, stream>>>(ed, es, bbaseD, bbaseS, x,
                                           rowptr, rsI, rsO, csr_src, xs, N_NODES_C);

    // ---- compute pipeline ---------------------------------------------
    k_agg1b<<<(N_NODES_C * 64 + 255) / 256, 256, 0, stream>>>(xs, rowptr, csr_src, rsI, agg1b, N_NODES_C);
    k_mfma <<<(N_NODES_C + 63) / 64, 256, 0, stream>>>(agg1b, b1, w1f, w2f, rsO, y, N_NODES_C);
    k_agg2p<<<(N_NODES_C + 31) / 32, 256, 0, stream>>>(y, rowptr, csr_src, rsI, gid, accbuf, N_NODES_C);
    k_fin  <<<1, 256, 0, stream>>>(accbuf, gid, b2, out, N_NODES_C);
}